// Round 2
// baseline (4213.947 us; speedup 1.0000x reference)
//
#include <hip/hip_runtime.h>
#include <stdint.h>

#define B_   64
#define T_   512
#define NI   64
#define H_   1024
#define TH_  256   // T_HARM
#define TS_  256   // T_SPIKE
#define NB   64    // blocks in cooperative harmonic kernel
#define CPB  16    // hidden columns per block (NB*CPB == H_)
#define BH   (B_ * H_)

#define DT_      0.042f
#define THRESH_  0.008f
#define RESET_   0.001f
#define SC_      256.0f            // 2^8 scale keeps fp16 residuals normal
#define ISC2_    (1.0f / 65536.0f) // exact 2^-16 unscale

typedef _Float16 f16x8 __attribute__((ext_vector_type(8)));
typedef float    f32x4 __attribute__((ext_vector_type(4)));

union H16 { _Float16 f; unsigned short u; };

// split v*SC_ into fp16 head + fp16 residual (22+ bit combined mantissa)
__device__ __forceinline__ void split2(float s, unsigned short& uh, unsigned short& ul) {
    _Float16 h = (_Float16)s;
    float r = s - (float)h;
    _Float16 l = (_Float16)r;
    H16 a, b; a.f = h; b.f = l;
    uh = a.u; ul = b.u;
}

// ---------------------------------------------------------------------------
// Kernel 1: xw_s[t][b][n] = x[b,t,:] @ x2h[:,n] with r2-spike's EXACT
// summation order (p0..p3 strided-4 fmaf, (p0+p1)+(p2+p3)) -> bit-identical
// xwv feeding the u-chain.
// ---------------------------------------------------------------------------
__global__ __launch_bounds__(256) void xw2_kernel(
    const float* __restrict__ x, const float* __restrict__ x2h,
    float* __restrict__ xw_s)
{
    const int n  = blockIdx.x * 256 + threadIdx.x;  // 0..1023
    const int b  = blockIdx.y;                      // 0..63
    const int t0 = blockIdx.z * 64;                 // 4 t-chunks

    float w2[NI];
    #pragma unroll
    for (int k = 0; k < NI; ++k) w2[k] = x2h[(size_t)k * H_ + n];

    const float* xb = x + (size_t)b * (T_ * NI);
    #pragma unroll 2
    for (int t = t0; t < t0 + 64; ++t) {
        const float* xt = xb + (size_t)t * NI;      // wave-uniform
        float p0 = 0.f, p1 = 0.f, p2 = 0.f, p3 = 0.f;
        #pragma unroll
        for (int k = 0; k < NI; k += 4) {
            p0 = fmaf(xt[k],     w2[k],     p0);
            p1 = fmaf(xt[k + 1], w2[k + 1], p1);
            p2 = fmaf(xt[k + 2], w2[k + 2], p2);
            p3 = fmaf(xt[k + 3], w2[k + 3], p3);
        }
        xw_s[(size_t)t * BH + (size_t)b * H_ + n] = (p0 + p1) + (p2 + p3);
    }
}

// ---------------------------------------------------------------------------
// Kernel 2: harmonic recurrence — r2 arithmetic bit-for-bit (fp16x2 xin MFMA,
// XT/X2 staging, update order, publish). Fence-free barrier validated R1
// (absmax unchanged).
//
// This round (schedule-only, no arithmetic change):
//  * sched_barrier(0) after the A prefetch loops. R1 evidence: VGPR_Count=132
//    despite a declared 256-VGPR prefetch -> the scheduler (which models
//    global-load latency at ~300cy, not the ~900cy cross-XCD/IF latency of
//    pub) sank the 64 loads next to their MFMA consumers, collapsing the
//    pipeline to a few in-flight loads: 64 x 900/D cyc ~ 9 us/step of pure
//    stall. Pinning all 64 issues before the first consumer forces the live
//    ranges to overlap (~310 VGPR, legal at 1 wave/SIMD) and turns the
//    stream into ~ L + 64*issue ~ 0.5 us.
//  * XT staging loads issued before the trajectory stores in the post-flag
//    window (loads earlier; stores are fire-and-forget).
// ---------------------------------------------------------------------------
__global__ __launch_bounds__(256, 1) void harm_kernel(
    const float* __restrict__ x,    const float* __restrict__ x2h,
    const float* __restrict__ h2h,  const float* __restrict__ bias,
    const float* __restrict__ gam,  const float* __restrict__ eps,
    unsigned short* __restrict__ pub,   // [TH_+1][2][B][H] fp16 bits
    float* __restrict__ hys, float* __restrict__ hzs,
    float* __restrict__ hyW, float* __restrict__ hyf, float* __restrict__ hzf,
    int* __restrict__ flags)
{
    __shared__ __align__(16) unsigned short W3[2][CPB][1024]; // 64 KB h2h*SC split
    __shared__ __align__(16) unsigned short XT[2][2][4096];   // 32 KB xt*SC split (dbuf)
    __shared__ __align__(16) unsigned short X2[2][CPB][64];   //  4 KB x2h*SC split

    const int tid  = threadIdx.x;
    const int lane = tid & 63;
    const int wv   = tid >> 6;
    const int cb   = blockIdx.x * CPB;

    // ---- stage h2h[:, cb:cb+CPB] * SC, split hi/lo, XOR-swizzled (r2 verbatim) ----
    for (int idx = tid; idx < 1024 * CPB; idx += 256) {
        int c = idx & (CPB - 1);
        int k = idx >> 4;
        float w = h2h[(size_t)k * H_ + cb + c] * SC_;
        unsigned short hh, ll; split2(w, hh, ll);
        int el = c * 1024 + (((k >> 3) ^ (c & 7)) << 3) + (k & 7);
        W3[0][0][el] = hh;
        W3[1][0][el] = ll;
    }
    // ---- stage x2h[:, cb:cb+CPB] * SC (K=64) (r2 verbatim) ----
    for (int idx = tid; idx < 64 * CPB; idx += 256) {
        int c = idx & (CPB - 1);
        int k = idx >> 4;
        float w = x2h[(size_t)k * H_ + cb + c] * SC_;
        unsigned short hh, ll; split2(w, hh, ll);
        int el = c * 64 + (((k >> 3) ^ (c & 7)) << 3) + (k & 7);
        X2[0][0][el] = hh;
        X2[1][0][el] = ll;
    }

    // per-lane MFMA coordinates (validated r2)
    const int nloc = lane & 15;           // C/D col + B col
    const int ng   = cb + nloc;
    const int quad = lane >> 4;
    const int b0   = wv * 16 + quad * 4;  // C/D row = b0 + r
    const int arow = wv * 16 + nloc;      // A row (batch index)
    const int koff = quad * 8;            // A k-offset
    const float bsv = bias[ng], gmv = gam[ng], epv = eps[ng];

    float hy[4] = {0.f, 0.f, 0.f, 0.f};
    float hz[4] = {0.f, 0.f, 0.f, 0.f};

    // hy_0 = 0 publish (r2 verbatim)
    #pragma unroll
    for (int r = 0; r < 4; ++r) {
        __hip_atomic_store(&pub[(size_t)0 * BH + (size_t)(b0 + r) * H_ + ng],
                           (unsigned short)0, __ATOMIC_RELAXED, __HIP_MEMORY_SCOPE_AGENT);
        __hip_atomic_store(&pub[(size_t)1 * BH + (size_t)(b0 + r) * H_ + ng],
                           (unsigned short)0, __ATOMIC_RELAXED, __HIP_MEMORY_SCOPE_AGENT);
    }

    // stage xt for t=0 into buffer 0 (r2 verbatim)
    {
        for (int idx = tid; idx < 4096; idx += 256) {
            int b = idx >> 6, k = idx & 63;
            float v = x[(size_t)b * (T_ * NI) + 0 * NI + k] * SC_;
            unsigned short hh, ll; split2(v, hh, ll);
            int el = b * 64 + (((k >> 3) ^ (b & 7)) << 3) + (k & 7);
            XT[0][0][el] = hh;
            XT[0][1][el] = ll;
        }
    }

    // ---- initial barrier (publishes the zero state) ----
    __syncthreads();   // drains vmcnt: zero-publishes complete at coherence pt
    if (tid == 0)
        __hip_atomic_store(&flags[blockIdx.x], 1,
                           __ATOMIC_RELAXED, __HIP_MEMORY_SCOPE_AGENT);
    if (tid < NB) {
        while (__hip_atomic_load(&flags[tid], __ATOMIC_RELAXED,
                                 __HIP_MEMORY_SCOPE_AGENT) < 1)
            __builtin_amdgcn_s_sleep(1);
    }
    __syncthreads();
    __threadfence();   // ONE-TIME acquire: drop pre-kernel (poison) L2 lines

    for (int t = 0; t < TH_; ++t) {
        const int cur = t & 1;
        const unsigned short* ph = pub + ((size_t)t * 2 + 0) * BH + (size_t)arow * H_ + koff;
        const unsigned short* pl = pub + ((size_t)t * 2 + 1) * BH + (size_t)arow * H_ + koff;

        // ---- full-K prefetch of A into registers: ALL 64 loads issued before
        //      any consumer (sched_barrier pins them; ~310 VGPR, 1 wave/SIMD) ----
        f16x8 Ah[32], Al[32];
        #pragma unroll
        for (int c = 0; c < 32; ++c) Ah[c] = *(const f16x8*)(ph + c * 32);
        #pragma unroll
        for (int c = 0; c < 32; ++c) Al[c] = *(const f16x8*)(pl + c * 32);
        __builtin_amdgcn_sched_barrier(0);   // nothing crosses: loads stay issued up here

        // ---- xin = (xt*SC @ x2h*SC) via fp16x2 MFMA, K=64 (r2 verbatim;
        //      overlaps the A-load latency) ----
        f32x4 aX = {0.f, 0.f, 0.f, 0.f};
        #pragma unroll
        for (int kb = 0; kb < 64; kb += 32) {
            int pos = ((kb >> 3) + quad) ^ (nloc & 7);
            f16x8 ah = *(const f16x8*)&XT[cur][0][arow * 64 + pos * 8];
            f16x8 al = *(const f16x8*)&XT[cur][1][arow * 64 + pos * 8];
            f16x8 bh = *(const f16x8*)&X2[0][nloc][pos * 8];
            f16x8 bl = *(const f16x8*)&X2[1][nloc][pos * 8];
            aX = __builtin_amdgcn_mfma_f32_16x16x32_f16(ah, bh, aX, 0, 0, 0);
            aX = __builtin_amdgcn_mfma_f32_16x16x32_f16(ah, bl, aX, 0, 0, 0);
            aX = __builtin_amdgcn_mfma_f32_16x16x32_f16(al, bh, aX, 0, 0, 0);
        }

        // ---- hy @ h2h via fp16x2 MFMA, K=1024 (same accumulate order as r2) ----
        f32x4 aH = {0.f, 0.f, 0.f, 0.f};
        #pragma unroll
        for (int c = 0; c < 32; ++c) {
            int pos = (c * 4 + quad) ^ (nloc & 7);
            f16x8 bh = *(const f16x8*)&W3[0][nloc][pos * 8];
            f16x8 bl = *(const f16x8*)&W3[1][nloc][pos * 8];
            aH = __builtin_amdgcn_mfma_f32_16x16x32_f16(Ah[c], bh, aH, 0, 0, 0);
            aH = __builtin_amdgcn_mfma_f32_16x16x32_f16(Ah[c], bl, aH, 0, 0, 0);
            aH = __builtin_amdgcn_mfma_f32_16x16x32_f16(Al[c], bh, aH, 0, 0, 0);
        }

        unsigned short* pnh = pub + ((size_t)(t + 1) * 2 + 0) * BH;
        unsigned short* pnl = pub + ((size_t)(t + 1) * 2 + 1) * BH;

        // ---- state update + publish ONLY (r2 arithmetic verbatim) ----
        #pragma unroll
        for (int r = 0; r < 4; ++r) {
            int b = b0 + r;
            float hyr = hy[r], hzr = hz[r];
            float th;
            {
                #pragma clang fp contract(off)
                float xinv = aX[r] * ISC2_;        // exact unscale (r2 verbatim)
                float hywv = aH[r] * ISC2_;        // exact unscale
                float arg  = (xinv + hywv) + bsv;  // np order
                th = tanhf(arg);
                float g = gmv * hyr;
                float e = epv * hzr;
                float d = (th - g) - e;
                hzr = hzr + DT_ * d;
                hyr = hyr + DT_ * hzr;
            }
            hy[r] = hyr; hz[r] = hzr;
            unsigned short hh, ll; split2(hyr * SC_, hh, ll);
            __hip_atomic_store(&pnh[(size_t)b * H_ + ng], hh,
                               __ATOMIC_RELAXED, __HIP_MEMORY_SCOPE_AGENT);
            __hip_atomic_store(&pnl[(size_t)b * H_ + ng], ll,
                               __ATOMIC_RELAXED, __HIP_MEMORY_SCOPE_AGENT);
        }

        // ---- release: drain ONLY the publish stores, then raise the flag ----
        __syncthreads();   // vmcnt(0): pub stores complete at coherence pt
        if (tid == 0)
            __hip_atomic_store(&flags[blockIdx.x], t + 2,
                               __ATOMIC_RELAXED, __HIP_MEMORY_SCOPE_AGENT);

        // ---- off-critical-path: stage xt for t+1 first (loads issue early;
        //      x is L2-hot: no per-step invalidation) ----
        if (t + 1 < TH_) {
            for (int idx = tid; idx < 4096; idx += 256) {
                int b = idx >> 6, k = idx & 63;
                float v = x[(size_t)b * (T_ * NI) + (size_t)(t + 1) * NI + k] * SC_;
                unsigned short hh, ll; split2(v, hh, ll);
                int el = b * 64 + (((k >> 3) ^ (b & 7)) << 3) + (k & 7);
                XT[1 - cur][0][el] = hh;
                XT[1 - cur][1][el] = ll;
            }
        }

        // ---- off-critical-path: trajectory stores (fire-and-forget; drained
        //      by NEXT step's __syncthreads) ----
        #pragma unroll
        for (int r = 0; r < 4; ++r) {
            int b = b0 + r;
            hys[(size_t)b * (T_ * H_) + (size_t)t * H_ + ng] = hy[r];
            hzs[(size_t)b * (T_ * H_) + (size_t)t * H_ + ng] = hz[r];
        }

        // ---- wait for all publishers ----
        if (tid < NB) {
            while (__hip_atomic_load(&flags[tid], __ATOMIC_RELAXED,
                                     __HIP_MEMORY_SCOPE_AGENT) < t + 2)
                __builtin_amdgcn_s_sleep(1);
        }
        __syncthreads();   // also makes XT staging visible to all waves
    }

    // ---- hyW = hy_final @ h2h (from pub[256]); export final state (r2 verbatim
    //      arithmetic; same full-prefetch schedule as the main loop) ----
    {
        const unsigned short* ph = pub + ((size_t)TH_ * 2 + 0) * BH + (size_t)arow * H_ + koff;
        const unsigned short* pl = pub + ((size_t)TH_ * 2 + 1) * BH + (size_t)arow * H_ + koff;
        f16x8 Ah[32], Al[32];
        #pragma unroll
        for (int c = 0; c < 32; ++c) Ah[c] = *(const f16x8*)(ph + c * 32);
        #pragma unroll
        for (int c = 0; c < 32; ++c) Al[c] = *(const f16x8*)(pl + c * 32);
        __builtin_amdgcn_sched_barrier(0);
        f32x4 aH = {0.f, 0.f, 0.f, 0.f};
        #pragma unroll
        for (int c = 0; c < 32; ++c) {
            int pos = (c * 4 + quad) ^ (nloc & 7);
            f16x8 bh = *(const f16x8*)&W3[0][nloc][pos * 8];
            f16x8 bl = *(const f16x8*)&W3[1][nloc][pos * 8];
            aH = __builtin_amdgcn_mfma_f32_16x16x32_f16(Ah[c], bh, aH, 0, 0, 0);
            aH = __builtin_amdgcn_mfma_f32_16x16x32_f16(Ah[c], bl, aH, 0, 0, 0);
            aH = __builtin_amdgcn_mfma_f32_16x16x32_f16(Al[c], bh, aH, 0, 0, 0);
        }
        #pragma unroll
        for (int r = 0; r < 4; ++r) {
            int b = b0 + r;
            hyW[(size_t)b * H_ + ng] = aH[r] * ISC2_;
            hyf[(size_t)b * H_ + ng] = hy[r];
            hzf[(size_t)b * H_ + ng] = hz[r];
        }
    }
}

// ---------------------------------------------------------------------------
// Kernel 3: spiking (LIF) phase. u-chain r2-verbatim; xwv is bit-identical to
// r2's in-register dot (from xw2_kernel). Writes ONLY the chain-dependent
// us/sp streams (hys/hzs tails in tail_kernel at full occupancy).
// ---------------------------------------------------------------------------
__global__ __launch_bounds__(256) void spike_kernel(
    const float* __restrict__ xw_s, const float* __restrict__ hyW,
    float* __restrict__ us,  float* __restrict__ sp)
{
    const int n = blockIdx.x * 256 + threadIdx.x;   // 0..1023
    const int b = blockIdx.y;                       // 0..63
    const float w = hyW[(size_t)b * H_ + n];

    float u = 0.f;
    float*       usp = us + (size_t)b * (TS_ * H_) + n;
    float*       spp = sp + (size_t)b * (TS_ * H_) + n;
    const float* xwp = xw_s + (size_t)b * H_ + n;

    #pragma unroll 4
    for (int t = 0; t < TS_; ++t) {
        float xwv = xwp[(size_t)t * BH];
        float spike, un = u;
        {
            #pragma clang fp contract(off)
            spike = (un > THRESH_) ? 1.f : 0.f;    // r2 verbatim
            un = (spike == 1.f) ? RESET_ : un;
            float s0 = (-un + w) + xwv;
            float m1 = s0 * 0.025f;
            float m2 = m1 * 0.042f;
            un = un + m2;
        }
        u = un;
        usp[(size_t)t * H_] = u;
        spp[(size_t)t * H_] = spike;
    }
}

// ---------------------------------------------------------------------------
// Kernel 4: broadcast hy/hz final state across the spiking-phase tail of the
// trajectories. Pure BW kernel (134 MB of constant writes) at full occupancy.
// ---------------------------------------------------------------------------
__global__ __launch_bounds__(256) void tail_kernel(
    const float* __restrict__ hyf, const float* __restrict__ hzf,
    float* __restrict__ hys, float* __restrict__ hzs)
{
    const int t  = blockIdx.x;    // 0..255
    const int b  = blockIdx.y;    // 0..63
    const int n4 = threadIdx.x;   // 0..255 (float4 index)

    const float4 hv = ((const float4*)(hyf + (size_t)b * H_))[n4];
    const float4 zv = ((const float4*)(hzf + (size_t)b * H_))[n4];
    const size_t row = (size_t)b * (T_ * H_) + (size_t)(TH_ + t) * H_;
    ((float4*)(hys + row))[n4] = hv;
    ((float4*)(hzs + row))[n4] = zv;
}

// ---------------------------------------------------------------------------
extern "C" void kernel_launch(void* const* d_in, const int* in_sizes, int n_in,
                              void* d_out, int out_size, void* d_ws, size_t ws_size,
                              hipStream_t stream)
{
    (void)in_sizes; (void)n_in; (void)out_size; (void)ws_size;

    const float* x    = (const float*)d_in[0];
    const float* x2h  = (const float*)d_in[1];
    const float* h2h  = (const float*)d_in[2];
    const float* bias = (const float*)d_in[3];
    const float* gam  = (const float*)d_in[4];
    const float* eps  = (const float*)d_in[5];

    float* out = (float*)d_out;
    float* hys = out;                                  // (64,512,1024)
    float* hzs = out + (size_t)B_ * T_ * H_;           // (64,512,1024)
    float* us  = out + 2 * (size_t)B_ * T_ * H_;       // (64,256,1024)
    float* sp  = us  + (size_t)B_ * TS_ * H_;          // (64,256,1024)

    char* ws = (char*)d_ws;
    float*          xw_s = (float*)ws;                         //  67,108,864 B
    unsigned short* pub  = (unsigned short*)(ws + 67108864);   //  67,371,008 B
    float*          hyW  = (float*)(ws + 134479872);           //     262,144 B
    float*          hyf  = (float*)(ws + 134479872 + 262144);  //     262,144 B
    float*          hzf  = (float*)(ws + 134479872 + 524288);  //     262,144 B
    int*            flg  = (int*)(ws + 134479872 + 786432);    //       4,096 B

    hipMemsetAsync(flg, 0, 4096, stream);   // flag array (ws is poisoned)

    xw2_kernel <<<dim3(4, 64, 4), 256, 0, stream>>>(x, x2h, xw_s);
    harm_kernel<<<dim3(NB), 256, 0, stream>>>(x, x2h, h2h, bias, gam, eps,
                                              pub, hys, hzs, hyW, hyf, hzf, flg);
    tail_kernel<<<dim3(256, 64), 256, 0, stream>>>(hyf, hzf, hys, hzs);
    spike_kernel<<<dim3(4, 64), 256, 0, stream>>>(xw_s, hyW, us, sp);
}

// Round 3
// 3083.107 us; speedup vs baseline: 1.3668x; 1.3668x over previous
//
#include <hip/hip_runtime.h>
#include <stdint.h>

#define B_   64
#define T_   512
#define NI   64
#define H_   1024
#define TH_  256   // T_HARM
#define TS_  256   // T_SPIKE
#define NB   64    // blocks in cooperative harmonic kernel
#define CPB  16    // hidden columns per block (NB*CPB == H_)
#define BH   (B_ * H_)

#define DT_      0.042f
#define THRESH_  0.008f
#define RESET_   0.001f
#define SC_      256.0f            // 2^8 scale keeps fp16 residuals normal
#define ISC2_    (1.0f / 65536.0f) // exact 2^-16 unscale

typedef _Float16 f16x8 __attribute__((ext_vector_type(8)));
typedef float    f32x4 __attribute__((ext_vector_type(4)));

union H16 { _Float16 f; unsigned short u; };

// split v*SC_ into fp16 head + fp16 residual (22+ bit combined mantissa)
__device__ __forceinline__ void split2(float s, unsigned short& uh, unsigned short& ul) {
    _Float16 h = (_Float16)s;
    float r = s - (float)h;
    _Float16 l = (_Float16)r;
    H16 a, b; a.f = h; b.f = l;
    uh = a.u; ul = b.u;
}

// ---------------------------------------------------------------------------
// Kernel 1: xw_s[t][b][n] = x[b,t,:] @ x2h[:,n] with r2-spike's EXACT
// summation order -> bit-identical xwv feeding the u-chain.
// ---------------------------------------------------------------------------
__global__ __launch_bounds__(256) void xw2_kernel(
    const float* __restrict__ x, const float* __restrict__ x2h,
    float* __restrict__ xw_s)
{
    const int n  = blockIdx.x * 256 + threadIdx.x;  // 0..1023
    const int b  = blockIdx.y;                      // 0..63
    const int t0 = blockIdx.z * 64;                 // 4 t-chunks

    float w2[NI];
    #pragma unroll
    for (int k = 0; k < NI; ++k) w2[k] = x2h[(size_t)k * H_ + n];

    const float* xb = x + (size_t)b * (T_ * NI);
    #pragma unroll 2
    for (int t = t0; t < t0 + 64; ++t) {
        const float* xt = xb + (size_t)t * NI;      // wave-uniform
        float p0 = 0.f, p1 = 0.f, p2 = 0.f, p3 = 0.f;
        #pragma unroll
        for (int k = 0; k < NI; k += 4) {
            p0 = fmaf(xt[k],     w2[k],     p0);
            p1 = fmaf(xt[k + 1], w2[k + 1], p1);
            p2 = fmaf(xt[k + 2], w2[k + 2], p2);
            p3 = fmaf(xt[k + 3], w2[k + 3], p3);
        }
        xw_s[(size_t)t * BH + (size_t)b * H_ + n] = (p0 + p1) + (p2 + p3);
    }
}

// ---------------------------------------------------------------------------
// Kernel 2: harmonic recurrence — arithmetic bit-for-bit identical to R1
// (same MFMA sequence/order, same staging values, same update ops).
//
// Sync redesign this round (R2 post-mortem: pinning loads lost the aX
// overlap and starved registers; revert pin, restructure sync instead):
//  * trailing block barrier REMOVED. Acquire wait is per-WAVE: each lane
//    polls flags[lane] (one vector sc1 load per round, exec-mask loop),
//    own block exempt (its pub stores drained at the release syncthreads).
//  * XT staging is WAVE-LOCAL: wave wv stages exactly the 16 batch rows
//    (arow in [wv*16, wv*16+16)) that only it reads. Same values, same
//    LDS slots -> no cross-wave XT dependency, no barrier needed for it
//    (same-wave ds_write->ds_read ordered by lgkmcnt).
//  * A-loads: explicit 2-buffer group pipeline (4 groups x 8 c's). Issue
//    groups 0+1 (32 loads in flight), run aX (LDS-only) as latency cover,
//    then consume/load alternately. No sched_barrier; an asm memory
//    clobber after the poll keeps pub loads from hoisting above the wait
//    (HW order is given by the poll branch's waitcnt).
//  * Only remaining block-wide sync: the release __syncthreads (vmcnt(0)
//    drain of pub stores) before the flag store.
// ---------------------------------------------------------------------------
__global__ __launch_bounds__(256, 1) void harm_kernel(
    const float* __restrict__ x,    const float* __restrict__ x2h,
    const float* __restrict__ h2h,  const float* __restrict__ bias,
    const float* __restrict__ gam,  const float* __restrict__ eps,
    unsigned short* __restrict__ pub,   // [TH_+1][2][B][H] fp16 bits
    float* __restrict__ hys, float* __restrict__ hzs,
    float* __restrict__ hyW, float* __restrict__ hyf, float* __restrict__ hzf,
    int* __restrict__ flags)
{
    __shared__ __align__(16) unsigned short W3[2][CPB][1024]; // 64 KB h2h*SC split
    __shared__ __align__(16) unsigned short XT[2][2][4096];   // 32 KB xt*SC split (dbuf)
    __shared__ __align__(16) unsigned short X2[2][CPB][64];   //  4 KB x2h*SC split

    const int tid  = threadIdx.x;
    const int lane = tid & 63;
    const int wv   = tid >> 6;
    const int cb   = blockIdx.x * CPB;
    const int bid  = blockIdx.x;

    // ---- stage h2h[:, cb:cb+CPB] * SC, split hi/lo, XOR-swizzled (verbatim) ----
    for (int idx = tid; idx < 1024 * CPB; idx += 256) {
        int c = idx & (CPB - 1);
        int k = idx >> 4;
        float w = h2h[(size_t)k * H_ + cb + c] * SC_;
        unsigned short hh, ll; split2(w, hh, ll);
        int el = c * 1024 + (((k >> 3) ^ (c & 7)) << 3) + (k & 7);
        W3[0][0][el] = hh;
        W3[1][0][el] = ll;
    }
    // ---- stage x2h[:, cb:cb+CPB] * SC (K=64) (verbatim) ----
    for (int idx = tid; idx < 64 * CPB; idx += 256) {
        int c = idx & (CPB - 1);
        int k = idx >> 4;
        float w = x2h[(size_t)k * H_ + cb + c] * SC_;
        unsigned short hh, ll; split2(w, hh, ll);
        int el = c * 64 + (((k >> 3) ^ (c & 7)) << 3) + (k & 7);
        X2[0][0][el] = hh;
        X2[1][0][el] = ll;
    }

    // per-lane MFMA coordinates (validated r2)
    const int nloc = lane & 15;           // C/D col + B col
    const int ng   = cb + nloc;
    const int quad = lane >> 4;
    const int b0   = wv * 16 + quad * 4;  // C/D row = b0 + r
    const int arow = wv * 16 + nloc;      // A row (batch index)
    const int koff = quad * 8;            // A k-offset
    const float bsv = bias[ng], gmv = gam[ng], epv = eps[ng];

    float hy[4] = {0.f, 0.f, 0.f, 0.f};
    float hz[4] = {0.f, 0.f, 0.f, 0.f};

    // hy_0 = 0 publish (verbatim)
    #pragma unroll
    for (int r = 0; r < 4; ++r) {
        __hip_atomic_store(&pub[(size_t)0 * BH + (size_t)(b0 + r) * H_ + ng],
                           (unsigned short)0, __ATOMIC_RELAXED, __HIP_MEMORY_SCOPE_AGENT);
        __hip_atomic_store(&pub[(size_t)1 * BH + (size_t)(b0 + r) * H_ + ng],
                           (unsigned short)0, __ATOMIC_RELAXED, __HIP_MEMORY_SCOPE_AGENT);
    }

    // stage xt for t=0 into buffer 0 (verbatim; block-wide OK: syncthreads follows)
    {
        for (int idx = tid; idx < 4096; idx += 256) {
            int b = idx >> 6, k = idx & 63;
            float v = x[(size_t)b * (T_ * NI) + 0 * NI + k] * SC_;
            unsigned short hh, ll; split2(v, hh, ll);
            int el = b * 64 + (((k >> 3) ^ (b & 7)) << 3) + (k & 7);
            XT[0][0][el] = hh;
            XT[0][1][el] = ll;
        }
    }

    // ---- initial release: drain zero-publish + staging, one-time acquire ----
    __syncthreads();   // vmcnt(0): zero-publishes complete at coherence pt
    __threadfence();   // ONE-TIME: drop pre-kernel (poison) L1/L2 lines
    if (tid == 0)
        __hip_atomic_store(&flags[bid], 1,
                           __ATOMIC_RELAXED, __HIP_MEMORY_SCOPE_AGENT);

    for (int t = 0; t < TH_; ++t) {
        const int cur = t & 1;
        const unsigned short* ph = pub + ((size_t)t * 2 + 0) * BH + (size_t)arow * H_ + koff;
        const unsigned short* pl = pub + ((size_t)t * 2 + 1) * BH + (size_t)arow * H_ + koff;

        // ---- per-wave acquire wait: all publishers of pub[t] visible.
        //      lane l polls flags[l]; own block exempt (drained at release). ----
        if (lane != bid) {
            while (__hip_atomic_load(&flags[lane], __ATOMIC_RELAXED,
                                     __HIP_MEMORY_SCOPE_AGENT) < t + 1)
                __builtin_amdgcn_s_sleep(1);
        }
        asm volatile("" ::: "memory");   // pub loads must not hoist above the wait

        // ---- A-load pipeline: issue groups 0+1 (32 loads in flight) ----
        f16x8 GAh[8], GAl[8], GBh[8], GBl[8];
        #pragma unroll
        for (int j = 0; j < 8; ++j) {
            GAh[j] = *(const f16x8*)(ph + j * 32);
            GAl[j] = *(const f16x8*)(pl + j * 32);
        }
        #pragma unroll
        for (int j = 0; j < 8; ++j) {
            GBh[j] = *(const f16x8*)(ph + (8 + j) * 32);
            GBl[j] = *(const f16x8*)(pl + (8 + j) * 32);
        }

        // ---- aX = (xt*SC @ x2h*SC), LDS-only: covers A-load latency (verbatim) ----
        f32x4 aX = {0.f, 0.f, 0.f, 0.f};
        #pragma unroll
        for (int kb = 0; kb < 64; kb += 32) {
            int pos = ((kb >> 3) + quad) ^ (nloc & 7);
            f16x8 ah = *(const f16x8*)&XT[cur][0][arow * 64 + pos * 8];
            f16x8 al = *(const f16x8*)&XT[cur][1][arow * 64 + pos * 8];
            f16x8 bh = *(const f16x8*)&X2[0][nloc][pos * 8];
            f16x8 bl = *(const f16x8*)&X2[1][nloc][pos * 8];
            aX = __builtin_amdgcn_mfma_f32_16x16x32_f16(ah, bh, aX, 0, 0, 0);
            aX = __builtin_amdgcn_mfma_f32_16x16x32_f16(ah, bl, aX, 0, 0, 0);
            aX = __builtin_amdgcn_mfma_f32_16x16x32_f16(al, bh, aX, 0, 0, 0);
        }

        // ---- hy @ h2h: consume/load pipeline, accumulate order c=0..31 (verbatim) ----
        f32x4 aH = {0.f, 0.f, 0.f, 0.f};
        // consume group 0 (c=0..7), then refill GA with group 2
        #pragma unroll
        for (int j = 0; j < 8; ++j) {
            int c = j;
            int pos = (c * 4 + quad) ^ (nloc & 7);
            f16x8 bh = *(const f16x8*)&W3[0][nloc][pos * 8];
            f16x8 bl = *(const f16x8*)&W3[1][nloc][pos * 8];
            aH = __builtin_amdgcn_mfma_f32_16x16x32_f16(GAh[j], bh, aH, 0, 0, 0);
            aH = __builtin_amdgcn_mfma_f32_16x16x32_f16(GAh[j], bl, aH, 0, 0, 0);
            aH = __builtin_amdgcn_mfma_f32_16x16x32_f16(GAl[j], bh, aH, 0, 0, 0);
        }
        #pragma unroll
        for (int j = 0; j < 8; ++j) {
            GAh[j] = *(const f16x8*)(ph + (16 + j) * 32);
            GAl[j] = *(const f16x8*)(pl + (16 + j) * 32);
        }
        // consume group 1 (c=8..15), refill GB with group 3
        #pragma unroll
        for (int j = 0; j < 8; ++j) {
            int c = 8 + j;
            int pos = (c * 4 + quad) ^ (nloc & 7);
            f16x8 bh = *(const f16x8*)&W3[0][nloc][pos * 8];
            f16x8 bl = *(const f16x8*)&W3[1][nloc][pos * 8];
            aH = __builtin_amdgcn_mfma_f32_16x16x32_f16(GBh[j], bh, aH, 0, 0, 0);
            aH = __builtin_amdgcn_mfma_f32_16x16x32_f16(GBh[j], bl, aH, 0, 0, 0);
            aH = __builtin_amdgcn_mfma_f32_16x16x32_f16(GBl[j], bh, aH, 0, 0, 0);
        }
        #pragma unroll
        for (int j = 0; j < 8; ++j) {
            GBh[j] = *(const f16x8*)(ph + (24 + j) * 32);
            GBl[j] = *(const f16x8*)(pl + (24 + j) * 32);
        }
        // consume group 2 (c=16..23)
        #pragma unroll
        for (int j = 0; j < 8; ++j) {
            int c = 16 + j;
            int pos = (c * 4 + quad) ^ (nloc & 7);
            f16x8 bh = *(const f16x8*)&W3[0][nloc][pos * 8];
            f16x8 bl = *(const f16x8*)&W3[1][nloc][pos * 8];
            aH = __builtin_amdgcn_mfma_f32_16x16x32_f16(GAh[j], bh, aH, 0, 0, 0);
            aH = __builtin_amdgcn_mfma_f32_16x16x32_f16(GAh[j], bl, aH, 0, 0, 0);
            aH = __builtin_amdgcn_mfma_f32_16x16x32_f16(GAl[j], bh, aH, 0, 0, 0);
        }
        // consume group 3 (c=24..31)
        #pragma unroll
        for (int j = 0; j < 8; ++j) {
            int c = 24 + j;
            int pos = (c * 4 + quad) ^ (nloc & 7);
            f16x8 bh = *(const f16x8*)&W3[0][nloc][pos * 8];
            f16x8 bl = *(const f16x8*)&W3[1][nloc][pos * 8];
            aH = __builtin_amdgcn_mfma_f32_16x16x32_f16(GBh[j], bh, aH, 0, 0, 0);
            aH = __builtin_amdgcn_mfma_f32_16x16x32_f16(GBh[j], bl, aH, 0, 0, 0);
            aH = __builtin_amdgcn_mfma_f32_16x16x32_f16(GBl[j], bh, aH, 0, 0, 0);
        }

        unsigned short* pnh = pub + ((size_t)(t + 1) * 2 + 0) * BH;
        unsigned short* pnl = pub + ((size_t)(t + 1) * 2 + 1) * BH;

        // ---- state update + publish (arithmetic verbatim) ----
        #pragma unroll
        for (int r = 0; r < 4; ++r) {
            int b = b0 + r;
            float hyr = hy[r], hzr = hz[r];
            float th;
            {
                #pragma clang fp contract(off)
                float xinv = aX[r] * ISC2_;        // exact unscale
                float hywv = aH[r] * ISC2_;        // exact unscale
                float arg  = (xinv + hywv) + bsv;  // np order
                th = tanhf(arg);
                float g = gmv * hyr;
                float e = epv * hzr;
                float d = (th - g) - e;
                hzr = hzr + DT_ * d;
                hyr = hyr + DT_ * hzr;
            }
            hy[r] = hyr; hz[r] = hzr;
            unsigned short hh, ll; split2(hyr * SC_, hh, ll);
            __hip_atomic_store(&pnh[(size_t)b * H_ + ng], hh,
                               __ATOMIC_RELAXED, __HIP_MEMORY_SCOPE_AGENT);
            __hip_atomic_store(&pnl[(size_t)b * H_ + ng], ll,
                               __ATOMIC_RELAXED, __HIP_MEMORY_SCOPE_AGENT);
        }

        // ---- release: drain pub stores (all waves), raise flag ----
        __syncthreads();   // vmcnt(0) per wave + block barrier
        if (tid == 0)
            __hip_atomic_store(&flags[bid], t + 2,
                               __ATOMIC_RELAXED, __HIP_MEMORY_SCOPE_AGENT);

        // ---- off-critical-path: trajectory stores (fire-and-forget) ----
        #pragma unroll
        for (int r = 0; r < 4; ++r) {
            int b = b0 + r;
            hys[(size_t)b * (T_ * H_) + (size_t)t * H_ + ng] = hy[r];
            hzs[(size_t)b * (T_ * H_) + (size_t)t * H_ + ng] = hz[r];
        }

        // ---- off-critical-path: WAVE-LOCAL xt staging for t+1 (same values,
        //      same slots as before; wave wv owns batches wv*16..wv*16+15;
        //      same-wave ds_write->ds_read needs no barrier) ----
        if (t + 1 < TH_) {
            #pragma unroll 4
            for (int i = 0; i < 16; ++i) {
                int b = wv * 16 + i, k = lane;
                float v = x[(size_t)b * (T_ * NI) + (size_t)(t + 1) * NI + k] * SC_;
                unsigned short hh, ll; split2(v, hh, ll);
                int el = b * 64 + (((k >> 3) ^ (b & 7)) << 3) + (k & 7);
                XT[1 - cur][0][el] = hh;
                XT[1 - cur][1][el] = ll;
            }
        }
        // NO trailing block barrier: next iteration's per-wave poll is the wait.
    }

    // ---- epilogue: wait for final publishers, hyW = hy_final @ h2h (verbatim
    //      arithmetic), export final state ----
    if (lane != bid) {
        while (__hip_atomic_load(&flags[lane], __ATOMIC_RELAXED,
                                 __HIP_MEMORY_SCOPE_AGENT) < TH_ + 1)
            __builtin_amdgcn_s_sleep(1);
    }
    asm volatile("" ::: "memory");
    {
        const unsigned short* ph = pub + ((size_t)TH_ * 2 + 0) * BH + (size_t)arow * H_ + koff;
        const unsigned short* pl = pub + ((size_t)TH_ * 2 + 1) * BH + (size_t)arow * H_ + koff;
        f32x4 aH = {0.f, 0.f, 0.f, 0.f};
        #pragma unroll 4
        for (int c = 0; c < 32; ++c) {
            f16x8 ah = *(const f16x8*)(ph + c * 32);
            f16x8 al = *(const f16x8*)(pl + c * 32);
            int pos = (c * 4 + quad) ^ (nloc & 7);
            f16x8 bh = *(const f16x8*)&W3[0][nloc][pos * 8];
            f16x8 bl = *(const f16x8*)&W3[1][nloc][pos * 8];
            aH = __builtin_amdgcn_mfma_f32_16x16x32_f16(ah, bh, aH, 0, 0, 0);
            aH = __builtin_amdgcn_mfma_f32_16x16x32_f16(ah, bl, aH, 0, 0, 0);
            aH = __builtin_amdgcn_mfma_f32_16x16x32_f16(al, bh, aH, 0, 0, 0);
        }
        #pragma unroll
        for (int r = 0; r < 4; ++r) {
            int b = b0 + r;
            hyW[(size_t)b * H_ + ng] = aH[r] * ISC2_;
            hyf[(size_t)b * H_ + ng] = hy[r];
            hzf[(size_t)b * H_ + ng] = hz[r];
        }
    }
}

// ---------------------------------------------------------------------------
// Kernel 3: spiking (LIF) phase. u-chain verbatim; xwv bit-identical (from
// xw2_kernel). Writes ONLY the chain-dependent us/sp streams.
// ---------------------------------------------------------------------------
__global__ __launch_bounds__(256) void spike_kernel(
    const float* __restrict__ xw_s, const float* __restrict__ hyW,
    float* __restrict__ us,  float* __restrict__ sp)
{
    const int n = blockIdx.x * 256 + threadIdx.x;   // 0..1023
    const int b = blockIdx.y;                       // 0..63
    const float w = hyW[(size_t)b * H_ + n];

    float u = 0.f;
    float*       usp = us + (size_t)b * (TS_ * H_) + n;
    float*       spp = sp + (size_t)b * (TS_ * H_) + n;
    const float* xwp = xw_s + (size_t)b * H_ + n;

    #pragma unroll 4
    for (int t = 0; t < TS_; ++t) {
        float xwv = xwp[(size_t)t * BH];
        float spike, un = u;
        {
            #pragma clang fp contract(off)
            spike = (un > THRESH_) ? 1.f : 0.f;    // verbatim
            un = (spike == 1.f) ? RESET_ : un;
            float s0 = (-un + w) + xwv;
            float m1 = s0 * 0.025f;
            float m2 = m1 * 0.042f;
            un = un + m2;
        }
        u = un;
        usp[(size_t)t * H_] = u;
        spp[(size_t)t * H_] = spike;
    }
}

// ---------------------------------------------------------------------------
// Kernel 4: broadcast hy/hz final state across the spiking-phase tail.
// Pure BW kernel (134 MB of constant writes) at full occupancy.
// ---------------------------------------------------------------------------
__global__ __launch_bounds__(256) void tail_kernel(
    const float* __restrict__ hyf, const float* __restrict__ hzf,
    float* __restrict__ hys, float* __restrict__ hzs)
{
    const int t  = blockIdx.x;    // 0..255
    const int b  = blockIdx.y;    // 0..63
    const int n4 = threadIdx.x;   // 0..255 (float4 index)

    const float4 hv = ((const float4*)(hyf + (size_t)b * H_))[n4];
    const float4 zv = ((const float4*)(hzf + (size_t)b * H_))[n4];
    const size_t row = (size_t)b * (T_ * H_) + (size_t)(TH_ + t) * H_;
    ((float4*)(hys + row))[n4] = hv;
    ((float4*)(hzs + row))[n4] = zv;
}

// ---------------------------------------------------------------------------
extern "C" void kernel_launch(void* const* d_in, const int* in_sizes, int n_in,
                              void* d_out, int out_size, void* d_ws, size_t ws_size,
                              hipStream_t stream)
{
    (void)in_sizes; (void)n_in; (void)out_size; (void)ws_size;

    const float* x    = (const float*)d_in[0];
    const float* x2h  = (const float*)d_in[1];
    const float* h2h  = (const float*)d_in[2];
    const float* bias = (const float*)d_in[3];
    const float* gam  = (const float*)d_in[4];
    const float* eps  = (const float*)d_in[5];

    float* out = (float*)d_out;
    float* hys = out;                                  // (64,512,1024)
    float* hzs = out + (size_t)B_ * T_ * H_;           // (64,512,1024)
    float* us  = out + 2 * (size_t)B_ * T_ * H_;       // (64,256,1024)
    float* sp  = us  + (size_t)B_ * TS_ * H_;          // (64,256,1024)

    char* ws = (char*)d_ws;
    float*          xw_s = (float*)ws;                         //  67,108,864 B
    unsigned short* pub  = (unsigned short*)(ws + 67108864);   //  67,371,008 B
    float*          hyW  = (float*)(ws + 134479872);           //     262,144 B
    float*          hyf  = (float*)(ws + 134479872 + 262144);  //     262,144 B
    float*          hzf  = (float*)(ws + 134479872 + 524288);  //     262,144 B
    int*            flg  = (int*)(ws + 134479872 + 786432);    //       4,096 B

    hipMemsetAsync(flg, 0, 4096, stream);   // flag array (ws is poisoned)

    xw2_kernel <<<dim3(4, 64, 4), 256, 0, stream>>>(x, x2h, xw_s);
    harm_kernel<<<dim3(NB), 256, 0, stream>>>(x, x2h, h2h, bias, gam, eps,
                                              pub, hys, hzs, hyW, hyf, hzf, flg);
    tail_kernel<<<dim3(256, 64), 256, 0, stream>>>(hyf, hzf, hys, hzs);
    spike_kernel<<<dim3(4, 64), 256, 0, stream>>>(xw_s, hyW, us, sp);
}

// Round 5
// 2664.380 us; speedup vs baseline: 1.5816x; 1.1572x over previous
//
#include <hip/hip_runtime.h>
#include <stdint.h>

#define B_   64
#define T_   512
#define NI   64
#define H_   1024
#define TH_  256   // T_HARM
#define TS_  256   // T_SPIKE
#define CPB  16    // hidden columns per block
#define BH   (B_ * H_)

#define DT_      0.042f
#define THRESH_  0.008f
#define RESET_   0.001f
#define SC_      256.0f            // 2^8 scale keeps fp16 residuals normal
#define ISC2_    (1.0f / 65536.0f) // exact 2^-16 unscale

typedef _Float16 f16x8 __attribute__((ext_vector_type(8)));
typedef float    f32x4 __attribute__((ext_vector_type(4)));

union H16 { _Float16 f; unsigned short u; };

// split v*SC_ into fp16 head + fp16 residual (22+ bit combined mantissa)
__device__ __forceinline__ void split2(float s, unsigned short& uh, unsigned short& ul) {
    _Float16 h = (_Float16)s;
    float r = s - (float)h;
    _Float16 l = (_Float16)r;
    H16 a, b; a.f = h; b.f = l;
    uh = a.u; ul = b.u;
}

// ---------------------------------------------------------------------------
// Kernel 1: xw_s[t][b][n] = x[b,t,:] @ x2h[:,n] with r2-spike's EXACT
// summation order -> bit-identical xwv feeding the u-chain.
// ---------------------------------------------------------------------------
__global__ __launch_bounds__(256) void xw2_kernel(
    const float* __restrict__ x, const float* __restrict__ x2h,
    float* __restrict__ xw_s)
{
    const int n  = blockIdx.x * 256 + threadIdx.x;  // 0..1023
    const int b  = blockIdx.y;                      // 0..63
    const int t0 = blockIdx.z * 64;                 // 4 t-chunks

    float w2[NI];
    #pragma unroll
    for (int k = 0; k < NI; ++k) w2[k] = x2h[(size_t)k * H_ + n];

    const float* xb = x + (size_t)b * (T_ * NI);
    #pragma unroll 2
    for (int t = t0; t < t0 + 64; ++t) {
        const float* xt = xb + (size_t)t * NI;      // wave-uniform
        float p0 = 0.f, p1 = 0.f, p2 = 0.f, p3 = 0.f;
        #pragma unroll
        for (int k = 0; k < NI; k += 4) {
            p0 = fmaf(xt[k],     w2[k],     p0);
            p1 = fmaf(xt[k + 1], w2[k + 1], p1);
            p2 = fmaf(xt[k + 2], w2[k + 2], p2);
            p3 = fmaf(xt[k + 3], w2[k + 3], p3);
        }
        xw_s[(size_t)t * BH + (size_t)b * H_ + n] = (p0 + p1) + (p2 + p3);
    }
}

// ---------------------------------------------------------------------------
// Kernel 2: harmonic recurrence, RETILED: grid = 4 batch-tiles x 64 col-tiles
// = 256 single-wave blocks (one per CU). Block (bi,bj) computes batches
// bi*16..bi*16+15 x cols bj*16..bj*16+15.
//
// Why: block (bi,bj) only READS pub rows bi*16..+15 (written solely by the
// 64 same-bi blocks) -> the 64-block all-to-all decomposes into 4 decoupled
// 64-block groups; pub read per CU drops 256KB -> 64KB/step (per-CU VMEM
// port floor 1.7 -> 0.43 us) and all 256 CUs carry MFMA work.
//
// Hang-safety audit (R4 re-submit): 256 blocks x 77824B LDS -> 2 blocks/CU
// capacity -> all blocks resident under any packing; flag protocol is
// monotonic with no cross-group wait -> no circular dependency; all index
// bounds verified. Numerics bit-identical to R3 (k-order, fragment mapping,
// swizzle keys arow&7==nloc&7, staged values, update ops unchanged).
//
// Single-wave blocks -> NO __syncthreads in the loop:
//   release = asm s_waitcnt vmcnt(0) (wave-level drain of the 8 pub sc1
//             stores) + flag store; acquire = per-lane poll of the group's
//             64 flags.
// ---------------------------------------------------------------------------
__global__ __launch_bounds__(64, 1) void harm_kernel(
    const float* __restrict__ x,    const float* __restrict__ x2h,
    const float* __restrict__ h2h,  const float* __restrict__ bias,
    const float* __restrict__ gam,  const float* __restrict__ eps,
    unsigned short* __restrict__ pub,   // [TH_+1][2][B][H] fp16 bits
    float* __restrict__ hys, float* __restrict__ hzs,
    float* __restrict__ hyW, float* __restrict__ hyf, float* __restrict__ hzf,
    int* __restrict__ flags)            // [4][64]
{
    __shared__ __align__(16) unsigned short W3[2][CPB][1024]; // 64 KB h2h*SC split
    __shared__ __align__(16) unsigned short XT[2][2][1024];   //  8 KB xt*SC split (16 batches, dbuf)
    __shared__ __align__(16) unsigned short X2[2][CPB][64];   //  4 KB x2h*SC split

    const int lane = threadIdx.x;       // 0..63 (one wave)
    const int bj   = blockIdx.x;        // col tile   0..63
    const int bi   = blockIdx.y;        // batch tile 0..3
    const int cb   = bj * CPB;
    const int fb   = bi * 64;           // flag-group base

    // ---- stage h2h[:, cb:cb+CPB] * SC, split hi/lo, XOR-swizzled (verbatim) ----
    for (int idx = lane; idx < 1024 * CPB; idx += 64) {
        int c = idx & (CPB - 1);
        int k = idx >> 4;
        float w = h2h[(size_t)k * H_ + cb + c] * SC_;
        unsigned short hh, ll; split2(w, hh, ll);
        int el = c * 1024 + (((k >> 3) ^ (c & 7)) << 3) + (k & 7);
        W3[0][0][el] = hh;
        W3[1][0][el] = ll;
    }
    // ---- stage x2h[:, cb:cb+CPB] * SC (K=64) (verbatim) ----
    for (int idx = lane; idx < 64 * CPB; idx += 64) {
        int c = idx & (CPB - 1);
        int k = idx >> 4;
        float w = x2h[(size_t)k * H_ + cb + c] * SC_;
        unsigned short hh, ll; split2(w, hh, ll);
        int el = c * 64 + (((k >> 3) ^ (c & 7)) << 3) + (k & 7);
        X2[0][0][el] = hh;
        X2[1][0][el] = ll;
    }

    // per-lane MFMA coordinates (same fragment mapping as before; batch base
    // is now bi*16 -- 16-aligned, so all &7 swizzle keys match)
    const int nloc = lane & 15;           // C/D col + B col (local)
    const int ng   = cb + nloc;           // global col
    const int quad = lane >> 4;
    const int b0   = bi * 16 + quad * 4;  // global C/D row = b0 + r
    const int arow = bi * 16 + nloc;      // global A row (batch) for pub
    const int koff = quad * 8;            // A k-offset
    const float bsv = bias[ng], gmv = gam[ng], epv = eps[ng];

    float hy[4] = {0.f, 0.f, 0.f, 0.f};
    float hz[4] = {0.f, 0.f, 0.f, 0.f};

    // hy_0 = 0 publish (this block's rows x cols; union over grid = full)
    #pragma unroll
    for (int r = 0; r < 4; ++r) {
        __hip_atomic_store(&pub[(size_t)0 * BH + (size_t)(b0 + r) * H_ + ng],
                           (unsigned short)0, __ATOMIC_RELAXED, __HIP_MEMORY_SCOPE_AGENT);
        __hip_atomic_store(&pub[(size_t)1 * BH + (size_t)(b0 + r) * H_ + ng],
                           (unsigned short)0, __ATOMIC_RELAXED, __HIP_MEMORY_SCOPE_AGENT);
    }

    // stage xt for t=0 into buffer 0 (wave-local: this block's 16 batches;
    // i&7 == b&7 since bi*16 is 16-aligned -> identical values & slots)
    {
        #pragma unroll 4
        for (int i = 0; i < 16; ++i) {
            int b = bi * 16 + i, k = lane;
            float v = x[(size_t)b * (T_ * NI) + 0 * NI + k] * SC_;
            unsigned short hh, ll; split2(v, hh, ll);
            int el = i * 64 + (((k >> 3) ^ (i & 7)) << 3) + (k & 7);
            XT[0][0][el] = hh;
            XT[0][1][el] = ll;
        }
    }

    // ---- initial release: drain zero-publish, one-time poison inv, flag=1 ----
    asm volatile("s_waitcnt vmcnt(0)" ::: "memory");
    __threadfence();   // ONE-TIME: drop pre-kernel (poison) L1/L2 lines
    if (lane == 0)
        __hip_atomic_store(&flags[fb + bj], 1,
                           __ATOMIC_RELAXED, __HIP_MEMORY_SCOPE_AGENT);

    for (int t = 0; t < TH_; ++t) {
        const int cur = t & 1;
        const unsigned short* ph = pub + ((size_t)t * 2 + 0) * BH + (size_t)arow * H_ + koff;
        const unsigned short* pl = pub + ((size_t)t * 2 + 1) * BH + (size_t)arow * H_ + koff;

        // ---- acquire: poll the 64 producers of THIS bi-group (lane l polls
        //      flags[fb+l]; own flag stored earlier by this wave) ----
        while (__hip_atomic_load(&flags[fb + lane], __ATOMIC_RELAXED,
                                 __HIP_MEMORY_SCOPE_AGENT) < t + 1)
            __builtin_amdgcn_s_sleep(1);
        asm volatile("" ::: "memory");   // pub loads must not hoist above the wait

        // ---- A-load pipeline: issue groups 0+1 (32 loads in flight) [R3 verbatim] ----
        f16x8 GAh[8], GAl[8], GBh[8], GBl[8];
        #pragma unroll
        for (int j = 0; j < 8; ++j) {
            GAh[j] = *(const f16x8*)(ph + j * 32);
            GAl[j] = *(const f16x8*)(pl + j * 32);
        }
        #pragma unroll
        for (int j = 0; j < 8; ++j) {
            GBh[j] = *(const f16x8*)(ph + (8 + j) * 32);
            GBl[j] = *(const f16x8*)(pl + (8 + j) * 32);
        }

        // ---- aX = (xt*SC @ x2h*SC), LDS-only: covers A-load latency (verbatim;
        //      XT row is the local batch index = nloc) ----
        f32x4 aX = {0.f, 0.f, 0.f, 0.f};
        #pragma unroll
        for (int kb = 0; kb < 64; kb += 32) {
            int pos = ((kb >> 3) + quad) ^ (nloc & 7);
            f16x8 ah = *(const f16x8*)&XT[cur][0][nloc * 64 + pos * 8];
            f16x8 al = *(const f16x8*)&XT[cur][1][nloc * 64 + pos * 8];
            f16x8 bh = *(const f16x8*)&X2[0][nloc][pos * 8];
            f16x8 bl = *(const f16x8*)&X2[1][nloc][pos * 8];
            aX = __builtin_amdgcn_mfma_f32_16x16x32_f16(ah, bh, aX, 0, 0, 0);
            aX = __builtin_amdgcn_mfma_f32_16x16x32_f16(ah, bl, aX, 0, 0, 0);
            aX = __builtin_amdgcn_mfma_f32_16x16x32_f16(al, bh, aX, 0, 0, 0);
        }

        // ---- hy @ h2h: consume/load pipeline, accumulate order c=0..31 (verbatim) ----
        f32x4 aH = {0.f, 0.f, 0.f, 0.f};
        #pragma unroll
        for (int j = 0; j < 8; ++j) {
            int c = j;
            int pos = (c * 4 + quad) ^ (nloc & 7);
            f16x8 bh = *(const f16x8*)&W3[0][nloc][pos * 8];
            f16x8 bl = *(const f16x8*)&W3[1][nloc][pos * 8];
            aH = __builtin_amdgcn_mfma_f32_16x16x32_f16(GAh[j], bh, aH, 0, 0, 0);
            aH = __builtin_amdgcn_mfma_f32_16x16x32_f16(GAh[j], bl, aH, 0, 0, 0);
            aH = __builtin_amdgcn_mfma_f32_16x16x32_f16(GAl[j], bh, aH, 0, 0, 0);
        }
        #pragma unroll
        for (int j = 0; j < 8; ++j) {
            GAh[j] = *(const f16x8*)(ph + (16 + j) * 32);
            GAl[j] = *(const f16x8*)(pl + (16 + j) * 32);
        }
        #pragma unroll
        for (int j = 0; j < 8; ++j) {
            int c = 8 + j;
            int pos = (c * 4 + quad) ^ (nloc & 7);
            f16x8 bh = *(const f16x8*)&W3[0][nloc][pos * 8];
            f16x8 bl = *(const f16x8*)&W3[1][nloc][pos * 8];
            aH = __builtin_amdgcn_mfma_f32_16x16x32_f16(GBh[j], bh, aH, 0, 0, 0);
            aH = __builtin_amdgcn_mfma_f32_16x16x32_f16(GBh[j], bl, aH, 0, 0, 0);
            aH = __builtin_amdgcn_mfma_f32_16x16x32_f16(GBl[j], bh, aH, 0, 0, 0);
        }
        #pragma unroll
        for (int j = 0; j < 8; ++j) {
            GBh[j] = *(const f16x8*)(ph + (24 + j) * 32);
            GBl[j] = *(const f16x8*)(pl + (24 + j) * 32);
        }
        #pragma unroll
        for (int j = 0; j < 8; ++j) {
            int c = 16 + j;
            int pos = (c * 4 + quad) ^ (nloc & 7);
            f16x8 bh = *(const f16x8*)&W3[0][nloc][pos * 8];
            f16x8 bl = *(const f16x8*)&W3[1][nloc][pos * 8];
            aH = __builtin_amdgcn_mfma_f32_16x16x32_f16(GAh[j], bh, aH, 0, 0, 0);
            aH = __builtin_amdgcn_mfma_f32_16x16x32_f16(GAh[j], bl, aH, 0, 0, 0);
            aH = __builtin_amdgcn_mfma_f32_16x16x32_f16(GAl[j], bh, aH, 0, 0, 0);
        }
        #pragma unroll
        for (int j = 0; j < 8; ++j) {
            int c = 24 + j;
            int pos = (c * 4 + quad) ^ (nloc & 7);
            f16x8 bh = *(const f16x8*)&W3[0][nloc][pos * 8];
            f16x8 bl = *(const f16x8*)&W3[1][nloc][pos * 8];
            aH = __builtin_amdgcn_mfma_f32_16x16x32_f16(GBh[j], bh, aH, 0, 0, 0);
            aH = __builtin_amdgcn_mfma_f32_16x16x32_f16(GBh[j], bl, aH, 0, 0, 0);
            aH = __builtin_amdgcn_mfma_f32_16x16x32_f16(GBl[j], bh, aH, 0, 0, 0);
        }

        unsigned short* pnh = pub + ((size_t)(t + 1) * 2 + 0) * BH;
        unsigned short* pnl = pub + ((size_t)(t + 1) * 2 + 1) * BH;

        // ---- state update + publish (arithmetic verbatim) ----
        #pragma unroll
        for (int r = 0; r < 4; ++r) {
            int b = b0 + r;
            float hyr = hy[r], hzr = hz[r];
            float th;
            {
                #pragma clang fp contract(off)
                float xinv = aX[r] * ISC2_;        // exact unscale
                float hywv = aH[r] * ISC2_;        // exact unscale
                float arg  = (xinv + hywv) + bsv;  // np order
                th = tanhf(arg);
                float g = gmv * hyr;
                float e = epv * hzr;
                float d = (th - g) - e;
                hzr = hzr + DT_ * d;
                hyr = hyr + DT_ * hzr;
            }
            hy[r] = hyr; hz[r] = hzr;
            unsigned short hh, ll; split2(hyr * SC_, hh, ll);
            __hip_atomic_store(&pnh[(size_t)b * H_ + ng], hh,
                               __ATOMIC_RELAXED, __HIP_MEMORY_SCOPE_AGENT);
            __hip_atomic_store(&pnl[(size_t)b * H_ + ng], ll,
                               __ATOMIC_RELAXED, __HIP_MEMORY_SCOPE_AGENT);
        }

        // ---- release: wave-level drain of pub stores, raise group flag ----
        asm volatile("s_waitcnt vmcnt(0)" ::: "memory");
        if (lane == 0)
            __hip_atomic_store(&flags[fb + bj], t + 2,
                               __ATOMIC_RELAXED, __HIP_MEMORY_SCOPE_AGENT);

        // ---- off-critical-path: trajectory stores (fire-and-forget) ----
        #pragma unroll
        for (int r = 0; r < 4; ++r) {
            int b = b0 + r;
            hys[(size_t)b * (T_ * H_) + (size_t)t * H_ + ng] = hy[r];
            hzs[(size_t)b * (T_ * H_) + (size_t)t * H_ + ng] = hz[r];
        }

        // ---- off-critical-path: wave-local xt staging for t+1 (same values,
        //      same slots; same-wave ds_write->ds_read ordered by lgkmcnt) ----
        if (t + 1 < TH_) {
            #pragma unroll 4
            for (int i = 0; i < 16; ++i) {
                int b = bi * 16 + i, k = lane;
                float v = x[(size_t)b * (T_ * NI) + (size_t)(t + 1) * NI + k] * SC_;
                unsigned short hh, ll; split2(v, hh, ll);
                int el = i * 64 + (((k >> 3) ^ (i & 7)) << 3) + (k & 7);
                XT[1 - cur][0][el] = hh;
                XT[1 - cur][1][el] = ll;
            }
        }
        // no block barrier: next iteration's poll is the only wait.
    }

    // ---- epilogue: wait for final publishers of this bi-group, then
    //      hyW = hy_final @ h2h (verbatim arithmetic), export final state ----
    while (__hip_atomic_load(&flags[fb + lane], __ATOMIC_RELAXED,
                             __HIP_MEMORY_SCOPE_AGENT) < TH_ + 1)
        __builtin_amdgcn_s_sleep(1);
    asm volatile("" ::: "memory");
    {
        const unsigned short* ph = pub + ((size_t)TH_ * 2 + 0) * BH + (size_t)arow * H_ + koff;
        const unsigned short* pl = pub + ((size_t)TH_ * 2 + 1) * BH + (size_t)arow * H_ + koff;
        f32x4 aH = {0.f, 0.f, 0.f, 0.f};
        #pragma unroll 4
        for (int c = 0; c < 32; ++c) {
            f16x8 ah = *(const f16x8*)(ph + c * 32);
            f16x8 al = *(const f16x8*)(pl + c * 32);
            int pos = (c * 4 + quad) ^ (nloc & 7);
            f16x8 bh = *(const f16x8*)&W3[0][nloc][pos * 8];
            f16x8 bl = *(const f16x8*)&W3[1][nloc][pos * 8];
            aH = __builtin_amdgcn_mfma_f32_16x16x32_f16(ah, bh, aH, 0, 0, 0);
            aH = __builtin_amdgcn_mfma_f32_16x16x32_f16(ah, bl, aH, 0, 0, 0);
            aH = __builtin_amdgcn_mfma_f32_16x16x32_f16(al, bh, aH, 0, 0, 0);
        }
        #pragma unroll
        for (int r = 0; r < 4; ++r) {
            int b = b0 + r;
            hyW[(size_t)b * H_ + ng] = aH[r] * ISC2_;
            hyf[(size_t)b * H_ + ng] = hy[r];
            hzf[(size_t)b * H_ + ng] = hz[r];
        }
    }
}

// ---------------------------------------------------------------------------
// Kernel 3: spiking (LIF) phase. u-chain verbatim; xwv bit-identical (from
// xw2_kernel). Writes ONLY the chain-dependent us/sp streams.
// ---------------------------------------------------------------------------
__global__ __launch_bounds__(256) void spike_kernel(
    const float* __restrict__ xw_s, const float* __restrict__ hyW,
    float* __restrict__ us,  float* __restrict__ sp)
{
    const int n = blockIdx.x * 256 + threadIdx.x;   // 0..1023
    const int b = blockIdx.y;                       // 0..63
    const float w = hyW[(size_t)b * H_ + n];

    float u = 0.f;
    float*       usp = us + (size_t)b * (TS_ * H_) + n;
    float*       spp = sp + (size_t)b * (TS_ * H_) + n;
    const float* xwp = xw_s + (size_t)b * H_ + n;

    #pragma unroll 4
    for (int t = 0; t < TS_; ++t) {
        float xwv = xwp[(size_t)t * BH];
        float spike, un = u;
        {
            #pragma clang fp contract(off)
            spike = (un > THRESH_) ? 1.f : 0.f;    // verbatim
            un = (spike == 1.f) ? RESET_ : un;
            float s0 = (-un + w) + xwv;
            float m1 = s0 * 0.025f;
            float m2 = m1 * 0.042f;
            un = un + m2;
        }
        u = un;
        usp[(size_t)t * H_] = u;
        spp[(size_t)t * H_] = spike;
    }
}

// ---------------------------------------------------------------------------
// Kernel 4: broadcast hy/hz final state across the spiking-phase tail.
// Pure BW kernel (134 MB of constant writes) at full occupancy.
// ---------------------------------------------------------------------------
__global__ __launch_bounds__(256) void tail_kernel(
    const float* __restrict__ hyf, const float* __restrict__ hzf,
    float* __restrict__ hys, float* __restrict__ hzs)
{
    const int t  = blockIdx.x;    // 0..255
    const int b  = blockIdx.y;    // 0..63
    const int n4 = threadIdx.x;   // 0..255 (float4 index)

    const float4 hv = ((const float4*)(hyf + (size_t)b * H_))[n4];
    const float4 zv = ((const float4*)(hzf + (size_t)b * H_))[n4];
    const size_t row = (size_t)b * (T_ * H_) + (size_t)(TH_ + t) * H_;
    ((float4*)(hys + row))[n4] = hv;
    ((float4*)(hzs + row))[n4] = zv;
}

// ---------------------------------------------------------------------------
extern "C" void kernel_launch(void* const* d_in, const int* in_sizes, int n_in,
                              void* d_out, int out_size, void* d_ws, size_t ws_size,
                              hipStream_t stream)
{
    (void)in_sizes; (void)n_in; (void)out_size; (void)ws_size;

    const float* x    = (const float*)d_in[0];
    const float* x2h  = (const float*)d_in[1];
    const float* h2h  = (const float*)d_in[2];
    const float* bias = (const float*)d_in[3];
    const float* gam  = (const float*)d_in[4];
    const float* eps  = (const float*)d_in[5];

    float* out = (float*)d_out;
    float* hys = out;                                  // (64,512,1024)
    float* hzs = out + (size_t)B_ * T_ * H_;           // (64,512,1024)
    float* us  = out + 2 * (size_t)B_ * T_ * H_;       // (64,256,1024)
    float* sp  = us  + (size_t)B_ * TS_ * H_;          // (64,256,1024)

    char* ws = (char*)d_ws;
    float*          xw_s = (float*)ws;                         //  67,108,864 B
    unsigned short* pub  = (unsigned short*)(ws + 67108864);   //  67,371,008 B
    float*          hyW  = (float*)(ws + 134479872);           //     262,144 B
    float*          hyf  = (float*)(ws + 134479872 + 262144);  //     262,144 B
    float*          hzf  = (float*)(ws + 134479872 + 524288);  //     262,144 B
    int*            flg  = (int*)(ws + 134479872 + 786432);    //       4,096 B

    hipMemsetAsync(flg, 0, 4096, stream);   // flag array (ws is poisoned)

    xw2_kernel <<<dim3(4, 64, 4), 256, 0, stream>>>(x, x2h, xw_s);
    harm_kernel<<<dim3(64, 4), 64, 0, stream>>>(x, x2h, h2h, bias, gam, eps,
                                                pub, hys, hzs, hyW, hyf, hzf, flg);
    tail_kernel<<<dim3(256, 64), 256, 0, stream>>>(hyf, hzf, hys, hzs);
    spike_kernel<<<dim3(4, 64), 256, 0, stream>>>(xw_s, hyW, us, sp);
}

// Round 6
// 1913.205 us; speedup vs baseline: 2.2026x; 1.3926x over previous
//
#include <hip/hip_runtime.h>
#include <stdint.h>

#define B_   64
#define T_   512
#define NI   64
#define H_   1024
#define TH_  256   // T_HARM
#define TS_  256   // T_SPIKE
#define CPB  16    // hidden columns per block
#define BH   (B_ * H_)

#define DT_      0.042f
#define THRESH_  0.008f
#define RESET_   0.001f
#define SC_      256.0f            // 2^8 scale keeps fp16 residuals normal
#define ISC2_    (1.0f / 65536.0f) // exact 2^-16 unscale

typedef _Float16 f16x8 __attribute__((ext_vector_type(8)));
typedef float    f32x4 __attribute__((ext_vector_type(4)));

union H16 { _Float16 f; unsigned short u; };

// split v*SC_ into fp16 head + fp16 residual (22+ bit combined mantissa)
__device__ __forceinline__ void split2(float s, unsigned short& uh, unsigned short& ul) {
    _Float16 h = (_Float16)s;
    float r = s - (float)h;
    _Float16 l = (_Float16)r;
    H16 a, b; a.f = h; b.f = l;
    uh = a.u; ul = b.u;
}

// ---------------------------------------------------------------------------
// Kernel 1: xw_s[t][b][n] = x[b,t,:] @ x2h[:,n] with r2-spike's EXACT
// summation order -> bit-identical xwv feeding the u-chain.
// ---------------------------------------------------------------------------
__global__ __launch_bounds__(256) void xw2_kernel(
    const float* __restrict__ x, const float* __restrict__ x2h,
    float* __restrict__ xw_s)
{
    const int n  = blockIdx.x * 256 + threadIdx.x;  // 0..1023
    const int b  = blockIdx.y;                      // 0..63
    const int t0 = blockIdx.z * 64;                 // 4 t-chunks

    float w2[NI];
    #pragma unroll
    for (int k = 0; k < NI; ++k) w2[k] = x2h[(size_t)k * H_ + n];

    const float* xb = x + (size_t)b * (T_ * NI);
    #pragma unroll 2
    for (int t = t0; t < t0 + 64; ++t) {
        const float* xt = xb + (size_t)t * NI;      // wave-uniform
        float p0 = 0.f, p1 = 0.f, p2 = 0.f, p3 = 0.f;
        #pragma unroll
        for (int k = 0; k < NI; k += 4) {
            p0 = fmaf(xt[k],     w2[k],     p0);
            p1 = fmaf(xt[k + 1], w2[k + 1], p1);
            p2 = fmaf(xt[k + 2], w2[k + 2], p2);
            p3 = fmaf(xt[k + 3], w2[k + 3], p3);
        }
        xw_s[(size_t)t * BH + (size_t)b * H_ + n] = (p0 + p1) + (p2 + p3);
    }
}

// ---------------------------------------------------------------------------
// Kernel 2: harmonic recurrence. R5 structure (4 bi-groups x 64 single-wave
// blocks, per-wave flag sync — validated, absmax bit-stable) with ONE change:
//
// A-STREAM VIA global_load_lds (R5 post-mortem: VGPR=132 for the third time
// proves the scheduler always collapses source-level register pipelines; the
// 64-load stream ran at depth ~6-8 against ~600-900cy cross-XCD latency =
// the missing ~7 us/step). global_load_lds has NO dest VGPR -> depth cannot
// be collapsed; all 64 issues ride vmcnt (HW depth 63): stream ~ issue+L
// ~ 0.5 us. LDS dest is linear (base + lane*16, m104/m108); the XOR swizzle
// is applied on the GLOBAL SOURCE address (m173 pattern): AH[row][p] holds
// pub[row][p ^ (row&7)], so the consumer index pos = (c*4+quad)^(nloc&7)
// (identical to W3's) yields pub[arow][c*4+quad] — a pure copy, bit-
// identical values in the identical MFMA order.
// aX (XT/X2, LDS-only) runs between issue and the vmcnt(0) as latency cover.
// LDS: 76.5 + 64 = 140 KB < 160 KB, still 1 block/CU.
// ---------------------------------------------------------------------------
__global__ __launch_bounds__(64, 1) void harm_kernel(
    const float* __restrict__ x,    const float* __restrict__ x2h,
    const float* __restrict__ h2h,  const float* __restrict__ bias,
    const float* __restrict__ gam,  const float* __restrict__ eps,
    unsigned short* __restrict__ pub,   // [TH_+1][2][B][H] fp16 bits
    float* __restrict__ hys, float* __restrict__ hzs,
    float* __restrict__ hyW, float* __restrict__ hyf, float* __restrict__ hzf,
    int* __restrict__ flags)            // [4][64]
{
    __shared__ __align__(16) unsigned short W3[2][CPB][1024]; // 64 KB h2h*SC split
    __shared__ __align__(16) unsigned short XT[2][2][1024];   //  8 KB xt*SC split (dbuf)
    __shared__ __align__(16) unsigned short X2[2][CPB][64];   //  4 KB x2h*SC split
    __shared__ __align__(16) unsigned short AH[16][1024];     // 32 KB A hi stage
    __shared__ __align__(16) unsigned short AL[16][1024];     // 32 KB A lo stage

    const int lane = threadIdx.x;       // 0..63 (one wave)
    const int bj   = blockIdx.x;        // col tile   0..63
    const int bi   = blockIdx.y;        // batch tile 0..3
    const int cb   = bj * CPB;
    const int fb   = bi * 64;           // flag-group base

    // ---- stage h2h[:, cb:cb+CPB] * SC, split hi/lo, XOR-swizzled (verbatim) ----
    for (int idx = lane; idx < 1024 * CPB; idx += 64) {
        int c = idx & (CPB - 1);
        int k = idx >> 4;
        float w = h2h[(size_t)k * H_ + cb + c] * SC_;
        unsigned short hh, ll; split2(w, hh, ll);
        int el = c * 1024 + (((k >> 3) ^ (c & 7)) << 3) + (k & 7);
        W3[0][0][el] = hh;
        W3[1][0][el] = ll;
    }
    // ---- stage x2h[:, cb:cb+CPB] * SC (K=64) (verbatim) ----
    for (int idx = lane; idx < 64 * CPB; idx += 64) {
        int c = idx & (CPB - 1);
        int k = idx >> 4;
        float w = x2h[(size_t)k * H_ + cb + c] * SC_;
        unsigned short hh, ll; split2(w, hh, ll);
        int el = c * 64 + (((k >> 3) ^ (c & 7)) << 3) + (k & 7);
        X2[0][0][el] = hh;
        X2[1][0][el] = ll;
    }

    // per-lane MFMA coordinates (validated)
    const int nloc = lane & 15;           // C/D col + B col (local)
    const int ng   = cb + nloc;           // global col
    const int quad = lane >> 4;
    const int b0   = bi * 16 + quad * 4;  // global C/D row = b0 + r
    const int arow = bi * 16 + nloc;      // global A row (batch) for pub
    const int koff = quad * 8;            // A k-offset
    const float bsv = bias[ng], gmv = gam[ng], epv = eps[ng];

    float hy[4] = {0.f, 0.f, 0.f, 0.f};
    float hz[4] = {0.f, 0.f, 0.f, 0.f};

    // hy_0 = 0 publish (this block's rows x cols; union over grid = full)
    #pragma unroll
    for (int r = 0; r < 4; ++r) {
        __hip_atomic_store(&pub[(size_t)0 * BH + (size_t)(b0 + r) * H_ + ng],
                           (unsigned short)0, __ATOMIC_RELAXED, __HIP_MEMORY_SCOPE_AGENT);
        __hip_atomic_store(&pub[(size_t)1 * BH + (size_t)(b0 + r) * H_ + ng],
                           (unsigned short)0, __ATOMIC_RELAXED, __HIP_MEMORY_SCOPE_AGENT);
    }

    // stage xt for t=0 into buffer 0 (wave-local; verbatim)
    {
        #pragma unroll 4
        for (int i = 0; i < 16; ++i) {
            int b = bi * 16 + i, k = lane;
            float v = x[(size_t)b * (T_ * NI) + 0 * NI + k] * SC_;
            unsigned short hh, ll; split2(v, hh, ll);
            int el = i * 64 + (((k >> 3) ^ (i & 7)) << 3) + (k & 7);
            XT[0][0][el] = hh;
            XT[0][1][el] = ll;
        }
    }

    // ---- initial release: drain zero-publish, one-time poison inv, flag=1 ----
    asm volatile("s_waitcnt vmcnt(0)" ::: "memory");
    __threadfence();   // ONE-TIME: drop pre-kernel (poison) L1/L2 lines
    if (lane == 0)
        __hip_atomic_store(&flags[fb + bj], 1,
                           __ATOMIC_RELAXED, __HIP_MEMORY_SCOPE_AGENT);

    for (int t = 0; t < TH_; ++t) {
        const int cur = t & 1;

        // ---- acquire: poll the 64 producers of THIS bi-group ----
        while (__hip_atomic_load(&flags[fb + lane], __ATOMIC_RELAXED,
                                 __HIP_MEMORY_SCOPE_AGENT) < t + 1)
            __builtin_amdgcn_s_sleep(1);
        asm volatile("" ::: "memory");   // pub accesses must not hoist above the wait

        // ---- A-stage: 64x global_load_lds (16B), depth held by vmcnt HW.
        //      LDS dest linear (base + lane*16); swizzle pre-applied on the
        //      global source: AH[row][p] <- pub_hi[bi*16+row][p ^ (row&7)]. ----
        {
            const unsigned short* srcH = pub + ((size_t)t * 2 + 0) * BH + (size_t)(bi * 16) * H_;
            const unsigned short* srcL = pub + ((size_t)t * 2 + 1) * BH + (size_t)(bi * 16) * H_;
            #pragma unroll
            for (int i = 0; i < 32; ++i) {
                const int row = i >> 1;
                const int p   = ((i & 1) << 6) + lane;            // 0..127
                const int gof = (row << 10) + ((p ^ (row & 7)) << 3); // u16 elems
                __builtin_amdgcn_global_load_lds(
                    (const __attribute__((address_space(1))) void*)(srcH + gof),
                    (__attribute__((address_space(3))) void*)(&AH[0][0] + (i << 9)),
                    16, 0, 0);
                __builtin_amdgcn_global_load_lds(
                    (const __attribute__((address_space(1))) void*)(srcL + gof),
                    (__attribute__((address_space(3))) void*)(&AL[0][0] + (i << 9)),
                    16, 0, 0);
            }
        }

        // ---- aX = (xt*SC @ x2h*SC), LDS-only: latency cover for the stage ----
        f32x4 aX = {0.f, 0.f, 0.f, 0.f};
        #pragma unroll
        for (int kb = 0; kb < 64; kb += 32) {
            int pos = ((kb >> 3) + quad) ^ (nloc & 7);
            f16x8 ah = *(const f16x8*)&XT[cur][0][nloc * 64 + pos * 8];
            f16x8 al = *(const f16x8*)&XT[cur][1][nloc * 64 + pos * 8];
            f16x8 bh = *(const f16x8*)&X2[0][nloc][pos * 8];
            f16x8 bl = *(const f16x8*)&X2[1][nloc][pos * 8];
            aX = __builtin_amdgcn_mfma_f32_16x16x32_f16(ah, bh, aX, 0, 0, 0);
            aX = __builtin_amdgcn_mfma_f32_16x16x32_f16(ah, bl, aX, 0, 0, 0);
            aX = __builtin_amdgcn_mfma_f32_16x16x32_f16(al, bh, aX, 0, 0, 0);
        }

        // ---- wait for the A-stage to land in LDS ----
        asm volatile("s_waitcnt vmcnt(0)" ::: "memory");

        // ---- hy @ h2h: accumulate order c=0..31, hi*bh, hi*bl, lo*bh
        //      (identical sequence and values as all prior rounds; A now
        //      read just-in-time from the LDS stage; pos index == W3's) ----
        f32x4 aH = {0.f, 0.f, 0.f, 0.f};
        #pragma unroll
        for (int c = 0; c < 32; ++c) {
            int pos = (c * 4 + quad) ^ (nloc & 7);
            f16x8 ah = *(const f16x8*)&AH[nloc][pos * 8];
            f16x8 al = *(const f16x8*)&AL[nloc][pos * 8];
            f16x8 bh = *(const f16x8*)&W3[0][nloc][pos * 8];
            f16x8 bl = *(const f16x8*)&W3[1][nloc][pos * 8];
            aH = __builtin_amdgcn_mfma_f32_16x16x32_f16(ah, bh, aH, 0, 0, 0);
            aH = __builtin_amdgcn_mfma_f32_16x16x32_f16(ah, bl, aH, 0, 0, 0);
            aH = __builtin_amdgcn_mfma_f32_16x16x32_f16(al, bh, aH, 0, 0, 0);
        }

        unsigned short* pnh = pub + ((size_t)(t + 1) * 2 + 0) * BH;
        unsigned short* pnl = pub + ((size_t)(t + 1) * 2 + 1) * BH;

        // ---- state update + publish (arithmetic verbatim) ----
        #pragma unroll
        for (int r = 0; r < 4; ++r) {
            int b = b0 + r;
            float hyr = hy[r], hzr = hz[r];
            float th;
            {
                #pragma clang fp contract(off)
                float xinv = aX[r] * ISC2_;        // exact unscale
                float hywv = aH[r] * ISC2_;        // exact unscale
                float arg  = (xinv + hywv) + bsv;  // np order
                th = tanhf(arg);
                float g = gmv * hyr;
                float e = epv * hzr;
                float d = (th - g) - e;
                hzr = hzr + DT_ * d;
                hyr = hyr + DT_ * hzr;
            }
            hy[r] = hyr; hz[r] = hzr;
            unsigned short hh, ll; split2(hyr * SC_, hh, ll);
            __hip_atomic_store(&pnh[(size_t)b * H_ + ng], hh,
                               __ATOMIC_RELAXED, __HIP_MEMORY_SCOPE_AGENT);
            __hip_atomic_store(&pnl[(size_t)b * H_ + ng], ll,
                               __ATOMIC_RELAXED, __HIP_MEMORY_SCOPE_AGENT);
        }

        // ---- release: wave-level drain of pub stores, raise group flag ----
        asm volatile("s_waitcnt vmcnt(0)" ::: "memory");
        if (lane == 0)
            __hip_atomic_store(&flags[fb + bj], t + 2,
                               __ATOMIC_RELAXED, __HIP_MEMORY_SCOPE_AGENT);

        // ---- off-critical-path: trajectory stores (fire-and-forget) ----
        #pragma unroll
        for (int r = 0; r < 4; ++r) {
            int b = b0 + r;
            hys[(size_t)b * (T_ * H_) + (size_t)t * H_ + ng] = hy[r];
            hzs[(size_t)b * (T_ * H_) + (size_t)t * H_ + ng] = hz[r];
        }

        // ---- off-critical-path: wave-local xt staging for t+1 (verbatim) ----
        if (t + 1 < TH_) {
            #pragma unroll 4
            for (int i = 0; i < 16; ++i) {
                int b = bi * 16 + i, k = lane;
                float v = x[(size_t)b * (T_ * NI) + (size_t)(t + 1) * NI + k] * SC_;
                unsigned short hh, ll; split2(v, hh, ll);
                int el = i * 64 + (((k >> 3) ^ (i & 7)) << 3) + (k & 7);
                XT[1 - cur][0][el] = hh;
                XT[1 - cur][1][el] = ll;
            }
        }
        // no block barrier: next iteration's poll is the only wait.
    }

    // ---- epilogue: wait for final publishers of this bi-group, then
    //      hyW = hy_final @ h2h (verbatim arithmetic), export final state ----
    while (__hip_atomic_load(&flags[fb + lane], __ATOMIC_RELAXED,
                             __HIP_MEMORY_SCOPE_AGENT) < TH_ + 1)
        __builtin_amdgcn_s_sleep(1);
    asm volatile("" ::: "memory");
    {
        const unsigned short* ph = pub + ((size_t)TH_ * 2 + 0) * BH + (size_t)arow * H_ + koff;
        const unsigned short* pl = pub + ((size_t)TH_ * 2 + 1) * BH + (size_t)arow * H_ + koff;
        f32x4 aH = {0.f, 0.f, 0.f, 0.f};
        #pragma unroll 4
        for (int c = 0; c < 32; ++c) {
            f16x8 ah = *(const f16x8*)(ph + c * 32);
            f16x8 al = *(const f16x8*)(pl + c * 32);
            int pos = (c * 4 + quad) ^ (nloc & 7);
            f16x8 bh = *(const f16x8*)&W3[0][nloc][pos * 8];
            f16x8 bl = *(const f16x8*)&W3[1][nloc][pos * 8];
            aH = __builtin_amdgcn_mfma_f32_16x16x32_f16(ah, bh, aH, 0, 0, 0);
            aH = __builtin_amdgcn_mfma_f32_16x16x32_f16(ah, bl, aH, 0, 0, 0);
            aH = __builtin_amdgcn_mfma_f32_16x16x32_f16(al, bh, aH, 0, 0, 0);
        }
        #pragma unroll
        for (int r = 0; r < 4; ++r) {
            int b = b0 + r;
            hyW[(size_t)b * H_ + ng] = aH[r] * ISC2_;
            hyf[(size_t)b * H_ + ng] = hy[r];
            hzf[(size_t)b * H_ + ng] = hz[r];
        }
    }
}

// ---------------------------------------------------------------------------
// Kernel 3: spiking (LIF) phase. u-chain verbatim; xwv bit-identical (from
// xw2_kernel). Writes ONLY the chain-dependent us/sp streams.
// ---------------------------------------------------------------------------
__global__ __launch_bounds__(256) void spike_kernel(
    const float* __restrict__ xw_s, const float* __restrict__ hyW,
    float* __restrict__ us,  float* __restrict__ sp)
{
    const int n = blockIdx.x * 256 + threadIdx.x;   // 0..1023
    const int b = blockIdx.y;                       // 0..63
    const float w = hyW[(size_t)b * H_ + n];

    float u = 0.f;
    float*       usp = us + (size_t)b * (TS_ * H_) + n;
    float*       spp = sp + (size_t)b * (TS_ * H_) + n;
    const float* xwp = xw_s + (size_t)b * H_ + n;

    #pragma unroll 4
    for (int t = 0; t < TS_; ++t) {
        float xwv = xwp[(size_t)t * BH];
        float spike, un = u;
        {
            #pragma clang fp contract(off)
            spike = (un > THRESH_) ? 1.f : 0.f;    // verbatim
            un = (spike == 1.f) ? RESET_ : un;
            float s0 = (-un + w) + xwv;
            float m1 = s0 * 0.025f;
            float m2 = m1 * 0.042f;
            un = un + m2;
        }
        u = un;
        usp[(size_t)t * H_] = u;
        spp[(size_t)t * H_] = spike;
    }
}

// ---------------------------------------------------------------------------
// Kernel 4: broadcast hy/hz final state across the spiking-phase tail.
// Pure BW kernel (134 MB of constant writes) at full occupancy.
// ---------------------------------------------------------------------------
__global__ __launch_bounds__(256) void tail_kernel(
    const float* __restrict__ hyf, const float* __restrict__ hzf,
    float* __restrict__ hys, float* __restrict__ hzs)
{
    const int t  = blockIdx.x;    // 0..255
    const int b  = blockIdx.y;    // 0..63
    const int n4 = threadIdx.x;   // 0..255 (float4 index)

    const float4 hv = ((const float4*)(hyf + (size_t)b * H_))[n4];
    const float4 zv = ((const float4*)(hzf + (size_t)b * H_))[n4];
    const size_t row = (size_t)b * (T_ * H_) + (size_t)(TH_ + t) * H_;
    ((float4*)(hys + row))[n4] = hv;
    ((float4*)(hzs + row))[n4] = zv;
}

// ---------------------------------------------------------------------------
extern "C" void kernel_launch(void* const* d_in, const int* in_sizes, int n_in,
                              void* d_out, int out_size, void* d_ws, size_t ws_size,
                              hipStream_t stream)
{
    (void)in_sizes; (void)n_in; (void)out_size; (void)ws_size;

    const float* x    = (const float*)d_in[0];
    const float* x2h  = (const float*)d_in[1];
    const float* h2h  = (const float*)d_in[2];
    const float* bias = (const float*)d_in[3];
    const float* gam  = (const float*)d_in[4];
    const float* eps  = (const float*)d_in[5];

    float* out = (float*)d_out;
    float* hys = out;                                  // (64,512,1024)
    float* hzs = out + (size_t)B_ * T_ * H_;           // (64,512,1024)
    float* us  = out + 2 * (size_t)B_ * T_ * H_;       // (64,256,1024)
    float* sp  = us  + (size_t)B_ * TS_ * H_;          // (64,256,1024)

    char* ws = (char*)d_ws;
    float*          xw_s = (float*)ws;                         //  67,108,864 B
    unsigned short* pub  = (unsigned short*)(ws + 67108864);   //  67,371,008 B
    float*          hyW  = (float*)(ws + 134479872);           //     262,144 B
    float*          hyf  = (float*)(ws + 134479872 + 262144);  //     262,144 B
    float*          hzf  = (float*)(ws + 134479872 + 524288);  //     262,144 B
    int*            flg  = (int*)(ws + 134479872 + 786432);    //       4,096 B

    hipMemsetAsync(flg, 0, 4096, stream);   // flag array (ws is poisoned)

    xw2_kernel <<<dim3(4, 64, 4), 256, 0, stream>>>(x, x2h, xw_s);
    harm_kernel<<<dim3(64, 4), 64, 0, stream>>>(x, x2h, h2h, bias, gam, eps,
                                                pub, hys, hzs, hyW, hyf, hzf, flg);
    tail_kernel<<<dim3(256, 64), 256, 0, stream>>>(hyf, hzf, hys, hzs);
    spike_kernel<<<dim3(4, 64), 256, 0, stream>>>(xw_s, hyW, us, sp);
}